// Round 1
// baseline (1050.896 us; speedup 1.0000x reference)
//
#include <hip/hip_runtime.h>
#include <hip/hip_bf16.h>

#define B 1024
#define H 1024
#define T 512
#define NUM 44
#define IN 128
#define AK (IN + 2 * H)   // 2176
#define G4 (4 * H)        // 4096

// ---------------- build attn_in = [x | emb0 | emb1 | emb2 | emb3 | h0[0] | c0[0]] ----------------
__global__ __launch_bounds__(256) void build_attn_in_kernel(
    const float* __restrict__ x, const int* __restrict__ x_emb,
    const float* __restrict__ h0, const float* __restrict__ c0,
    const float* __restrict__ e0, const float* __restrict__ e1,
    const float* __restrict__ e2, const float* __restrict__ e3,
    float* __restrict__ attn_in)
{
    int b = blockIdx.x;
    int id0 = x_emb[b * 4 + 0];
    int id1 = x_emb[b * 4 + 1];
    int id2 = x_emb[b * 4 + 2];
    int id3 = x_emb[b * 4 + 3];
    float* dst = attn_in + (size_t)b * AK;
    for (int j = threadIdx.x; j < AK; j += 256) {
        float v;
        if (j < 44)        v = x[b * NUM + j];
        else if (j < 108)  v = e0[id0 * 64 + (j - 44)];
        else if (j < 116)  v = e1[id1 * 8 + (j - 108)];
        else if (j < 124)  v = e2[id2 * 8 + (j - 116)];
        else if (j < 128)  v = e3[id3 * 4 + (j - 124)];
        else if (j < 1152) v = h0[b * H + (j - 128)];
        else               v = c0[b * H + (j - 1152)];
        dst[j] = v;
    }
}

// ---------------- generic f32 tiled GEMM: C[M][N] = X1@W1^T (+ X2@W2^T) + b1 (+ b2) ----------------
// X row-major M x K (leading dim ldx); W row-major N x K (leading dim ldw).
// BM=BN=64, BK=16, 256 threads, 4x4 per thread. Requires K % 16 == 0, M,N % 64 == 0.
#define BM 64
#define BN 64
#define BK 16

__global__ __launch_bounds__(256) void gemm_xwT_kernel(
    const float* __restrict__ X1, const float* __restrict__ W1,
    const float* __restrict__ X2, const float* __restrict__ W2,
    const float* __restrict__ bias1, const float* __restrict__ bias2,
    float* __restrict__ C,
    int K1, int ldx1, int ldw1,
    int K2, int ldx2, int ldw2,
    int N)
{
    __shared__ float As[BK][BM];
    __shared__ float Ws[BK][BN];
    const int tid = threadIdx.x;
    const int tx = tid & 15;   // col quad 0..15
    const int ty = tid >> 4;   // row quad 0..15
    const int m0 = blockIdx.y * BM;
    const int n0 = blockIdx.x * BN;

    float acc[4][4] = {};

    const int lidx = tid * 4;
    const int lr = lidx >> 4;   // 0..63 tile row
    const int lk = lidx & 15;   // 0,4,8,12

    for (int phase = 0; phase < 2; ++phase) {
        const float* X = phase ? X2 : X1;
        const float* W = phase ? W2 : W1;
        const int K   = phase ? K2 : K1;
        const int ldx = phase ? ldx2 : ldx1;
        const int ldw = phase ? ldw2 : ldw1;
        if (X == nullptr || K == 0) continue;

        for (int k0 = 0; k0 < K; k0 += BK) {
            float4 a = *(const float4*)(X + (size_t)(m0 + lr) * ldx + k0 + lk);
            float4 w = *(const float4*)(W + (size_t)(n0 + lr) * ldw + k0 + lk);
            As[lk + 0][lr] = a.x; As[lk + 1][lr] = a.y; As[lk + 2][lr] = a.z; As[lk + 3][lr] = a.w;
            Ws[lk + 0][lr] = w.x; Ws[lk + 1][lr] = w.y; Ws[lk + 2][lr] = w.z; Ws[lk + 3][lr] = w.w;
            __syncthreads();
            #pragma unroll
            for (int kk = 0; kk < BK; ++kk) {
                float4 av4 = *(const float4*)&As[kk][ty * 4];
                float4 wv4 = *(const float4*)&Ws[kk][tx * 4];
                float av[4] = {av4.x, av4.y, av4.z, av4.w};
                float wv[4] = {wv4.x, wv4.y, wv4.z, wv4.w};
                #pragma unroll
                for (int i = 0; i < 4; ++i)
                    #pragma unroll
                    for (int j = 0; j < 4; ++j)
                        acc[i][j] += av[i] * wv[j];
            }
            __syncthreads();
        }
    }

    #pragma unroll
    for (int i = 0; i < 4; ++i) {
        int row = m0 + ty * 4 + i;
        #pragma unroll
        for (int j = 0; j < 4; ++j) {
            int col = n0 + tx * 4 + j;
            float v = acc[i][j];
            if (bias1) v += bias1[col];
            if (bias2) v += bias2[col];
            C[(size_t)row * N + col] = v;
        }
    }
}

// ---------------- softmax over T=512 per row ----------------
__global__ __launch_bounds__(256) void softmax_kernel(
    const float* __restrict__ logits, float* __restrict__ aw)
{
    int b = blockIdx.x;
    const float* row = logits + (size_t)b * T;
    int tid = threadIdx.x;
    float v0 = row[tid];
    float v1 = row[tid + 256];
    float m = fmaxf(v0, v1);
    #pragma unroll
    for (int off = 32; off > 0; off >>= 1) m = fmaxf(m, __shfl_down(m, off, 64));
    __shared__ float sm[4];
    __shared__ float ss[4];
    if ((tid & 63) == 0) sm[tid >> 6] = m;
    __syncthreads();
    m = fmaxf(fmaxf(sm[0], sm[1]), fmaxf(sm[2], sm[3]));
    float e0 = expf(v0 - m), e1 = expf(v1 - m);
    float s = e0 + e1;
    #pragma unroll
    for (int off = 32; off > 0; off >>= 1) s += __shfl_down(s, off, 64);
    if ((tid & 63) == 0) ss[tid >> 6] = s;
    __syncthreads();
    s = ss[0] + ss[1] + ss[2] + ss[3];
    float inv = 1.0f / s;
    aw[(size_t)b * T + tid]       = e0 * inv;
    aw[(size_t)b * T + tid + 256] = e1 * inv;
}

// ---------------- ctx[b][h] = sum_t aw[b][t] * enc[t][b][h] ----------------
__global__ __launch_bounds__(256) void ctx_kernel(
    const float* __restrict__ enc, const float* __restrict__ aw,
    float* __restrict__ ctx)
{
    int b = blockIdx.x;
    __shared__ float w[T];
    for (int t = threadIdx.x; t < T; t += 256) w[t] = aw[(size_t)b * T + t];
    __syncthreads();
    int h0i = threadIdx.x * 4;
    const float* p = enc + (size_t)b * H + h0i;
    float4 acc = {0.f, 0.f, 0.f, 0.f};
    #pragma unroll 8
    for (int t = 0; t < T; ++t) {
        float4 v = *(const float4*)(p + (size_t)t * B * H);
        float s = w[t];
        acc.x += s * v.x; acc.y += s * v.y; acc.z += s * v.z; acc.w += s * v.w;
    }
    *(float4*)(ctx + (size_t)b * H + h0i) = acc;
}

// ---------------- LSTM pointwise: gates (i,f,g,o) -> h,c ----------------
__device__ __forceinline__ float sigmf(float v) { return 1.0f / (1.0f + expf(-v)); }

__global__ __launch_bounds__(256) void lstm_pointwise_kernel(
    const float* __restrict__ g, const float* __restrict__ c_in,
    float* __restrict__ h_out, float* __restrict__ c_out)
{
    int idx = blockIdx.x * 256 + threadIdx.x;   // 0 .. B*H-1
    int b = idx >> 10;
    int j = idx & 1023;
    const float* gr = g + (size_t)b * G4;
    float gi = gr[j];
    float gf = gr[j + H];
    float gc = gr[j + 2 * H];
    float go = gr[j + 3 * H];
    float c = sigmf(gf) * c_in[idx] + sigmf(gi) * tanhf(gc);
    float h = sigmf(go) * tanhf(c);
    h_out[idx] = h;
    c_out[idx] = c;
}

// ---------------- pred: out[b] = dot(h2[b], pred_w) + pred_b ----------------
__global__ __launch_bounds__(256) void pred_kernel(
    const float* __restrict__ h2, const float* __restrict__ pw,
    const float* __restrict__ pb, float* __restrict__ out)
{
    int b = blockIdx.x;
    const float* row = h2 + (size_t)b * H;
    float s = 0.f;
    for (int j = threadIdx.x; j < H; j += 256) s += row[j] * pw[j];
    #pragma unroll
    for (int off = 32; off > 0; off >>= 1) s += __shfl_down(s, off, 64);
    __shared__ float sm[4];
    if ((threadIdx.x & 63) == 0) sm[threadIdx.x >> 6] = s;
    __syncthreads();
    if (threadIdx.x == 0) out[b] = sm[0] + sm[1] + sm[2] + sm[3] + pb[0];
}

extern "C" void kernel_launch(void* const* d_in, const int* in_sizes, int n_in,
                              void* d_out, int out_size, void* d_ws, size_t ws_size,
                              hipStream_t stream) {
    const float* x      = (const float*)d_in[0];
    const int*   x_emb  = (const int*)d_in[1];
    const float* h0     = (const float*)d_in[2];   // (2,B,H)
    const float* c0     = (const float*)d_in[3];
    const float* enc    = (const float*)d_in[4];   // (T,B,H)
    const float* emb0   = (const float*)d_in[5];
    const float* emb1   = (const float*)d_in[6];
    const float* emb2   = (const float*)d_in[7];
    const float* emb3   = (const float*)d_in[8];
    const float* attn_w = (const float*)d_in[9];   // (T, 2176)
    const float* attn_b = (const float*)d_in[10];
    const float* comb_w = (const float*)d_in[11];  // (128, 1152)
    const float* comb_b = (const float*)d_in[12];
    const float* w_ih0  = (const float*)d_in[13];  // (4096,128)
    const float* w_hh0  = (const float*)d_in[14];  // (4096,1024)
    const float* b_ih0  = (const float*)d_in[15];
    const float* b_hh0  = (const float*)d_in[16];
    const float* w_ih1  = (const float*)d_in[17];  // (4096,1024)
    const float* w_hh1  = (const float*)d_in[18];
    const float* b_ih1  = (const float*)d_in[19];
    const float* b_hh1  = (const float*)d_in[20];
    const float* pred_w = (const float*)d_in[21];  // (1,1024)
    const float* pred_b = (const float*)d_in[22];

    float* out = (float*)d_out;
    const size_t BH = (size_t)B * H;           // 1048576
    float* h1_out = out + 1024;                // h_stack[0]
    float* h2_out = out + 1024 + BH;           // h_stack[1]
    float* c1_out = out + 1024 + 2 * BH;       // c_stack[0]
    float* c2_out = out + 1024 + 3 * BH;       // c_stack[1]
    float* aw_out = out + 1024 + 4 * BH;       // (B,T)

    float* ws = (float*)d_ws;
    float* attn_in = ws;                             // B*2176 = 2228224
    float* logits  = attn_in + (size_t)B * AK;       // B*512  = 524288
    float* ctx     = logits + (size_t)B * T;         // B*1024
    float* comb    = ctx + BH;                       // B*128
    float* g       = comb + (size_t)B * IN;          // B*4096
    // total ws use: 8,126,464 floats = 32.5 MB

    build_attn_in_kernel<<<B, 256, 0, stream>>>(x, x_emb, h0, c0, emb0, emb1, emb2, emb3, attn_in);

    // logits = attn_in @ attn_w^T + attn_b   (1024 x 512, K=2176)
    gemm_xwT_kernel<<<dim3(T / BN, B / BM), 256, 0, stream>>>(
        attn_in, attn_w, nullptr, nullptr, attn_b, nullptr, logits,
        AK, AK, AK, 0, 0, 0, T);

    softmax_kernel<<<B, 256, 0, stream>>>(logits, aw_out);

    ctx_kernel<<<B, 256, 0, stream>>>(enc, aw_out, ctx);

    // comb = [x_rnn | ctx] @ comb_w^T + comb_b   (1024 x 128)
    gemm_xwT_kernel<<<dim3(IN / BN, B / BM), 256, 0, stream>>>(
        attn_in, comb_w, ctx, comb_w + IN, comb_b, nullptr, comb,
        IN, AK, IN + H, H, H, IN + H, IN);

    // g1 = comb @ w_ih0^T + h0[0] @ w_hh0^T + b_ih0 + b_hh0   (1024 x 4096)
    gemm_xwT_kernel<<<dim3(G4 / BN, B / BM), 256, 0, stream>>>(
        comb, w_ih0, h0, w_hh0, b_ih0, b_hh0, g,
        IN, IN, IN, H, H, H, G4);

    lstm_pointwise_kernel<<<(B * H) / 256, 256, 0, stream>>>(g, c0, h1_out, c1_out);

    // g2 = h1 @ w_ih1^T + h0[1] @ w_hh1^T + b_ih1 + b_hh1
    gemm_xwT_kernel<<<dim3(G4 / BN, B / BM), 256, 0, stream>>>(
        h1_out, w_ih1, h0 + BH, w_hh1, b_ih1, b_hh1, g,
        H, H, H, H, H, H, G4);

    lstm_pointwise_kernel<<<(B * H) / 256, 256, 0, stream>>>(g, c0 + BH, h2_out, c2_out);

    pred_kernel<<<B, 256, 0, stream>>>(h2_out, pred_w, pred_b, out);
}

// Round 2
// 671.278 us; speedup vs baseline: 1.5655x; 1.5655x over previous
//
#include <hip/hip_runtime.h>
#include <hip/hip_bf16.h>

#define B 1024
#define H 1024
#define T 512
#define NUM 44
#define IN 128
#define AK (IN + 2 * H)   // 2176
#define G4 (4 * H)        // 4096

typedef __attribute__((ext_vector_type(8))) short s16x8;
typedef __attribute__((ext_vector_type(4))) float f32x4;

__device__ __forceinline__ unsigned short f2bf(float f) {
    unsigned u = __float_as_uint(f);
    unsigned r = (u + 0x7fffu + ((u >> 16) & 1u)) >> 16;
    return (unsigned short)r;
}

__device__ __forceinline__ void gload16(const ushort* g, ushort* l) {
    __builtin_amdgcn_global_load_lds(
        (const __attribute__((address_space(1))) void*)g,
        (__attribute__((address_space(3))) void*)l,
        16, 0, 0);
}

// ---------------- f32 -> bf16 bulk convert (n multiple of 4) ----------------
__global__ __launch_bounds__(256) void f32_to_bf16_kernel(
    const float* __restrict__ in, ushort* __restrict__ out, int n4)
{
    int i = blockIdx.x * 256 + threadIdx.x;
    if (i >= n4) return;
    float4 v = ((const float4*)in)[i];
    ushort4 o;
    o.x = f2bf(v.x); o.y = f2bf(v.y); o.z = f2bf(v.z); o.w = f2bf(v.w);
    ((ushort4*)out)[i] = o;
}

// ---------------- build attn_in (bf16) = [x | emb0..3 | h0[0] | c0[0]] ----------------
__global__ __launch_bounds__(256) void build_attn_in_kernel(
    const float* __restrict__ x, const int* __restrict__ x_emb,
    const float* __restrict__ h0, const float* __restrict__ c0,
    const float* __restrict__ e0, const float* __restrict__ e1,
    const float* __restrict__ e2, const float* __restrict__ e3,
    ushort* __restrict__ attn_in)
{
    int b = blockIdx.x;
    int id0 = x_emb[b * 4 + 0];
    int id1 = x_emb[b * 4 + 1];
    int id2 = x_emb[b * 4 + 2];
    int id3 = x_emb[b * 4 + 3];
    ushort* dst = attn_in + (size_t)b * AK;
    for (int j = threadIdx.x; j < AK; j += 256) {
        float v;
        if (j < 44)        v = x[b * NUM + j];
        else if (j < 108)  v = e0[id0 * 64 + (j - 44)];
        else if (j < 116)  v = e1[id1 * 8 + (j - 108)];
        else if (j < 124)  v = e2[id2 * 8 + (j - 116)];
        else if (j < 128)  v = e3[id3 * 4 + (j - 124)];
        else if (j < 1152) v = h0[b * H + (j - 128)];
        else               v = c0[b * H + (j - 1152)];
        dst[j] = f2bf(v);
    }
}

// ---------------- bf16 MFMA GEMM: C[M][N] = X1@W1^T (+ X2@W2^T) + b1 (+ b2) ----------------
// X row-major M x K (ld in elems), W row-major N x K. M=1024, N % 128 == 0, K % 32 == 0,
// all lds % 8 == 0 (16B row alignment for global_load_lds).
#define TM 128
#define TN 128
#define TK 32

__global__ __launch_bounds__(256) void mfma_gemm_kernel(
    const ushort* __restrict__ X1, const ushort* __restrict__ W1,
    const ushort* __restrict__ X2, const ushort* __restrict__ W2,
    const float* __restrict__ bias1, const float* __restrict__ bias2,
    float* __restrict__ Cf, ushort* __restrict__ Cb,
    int K1, int ldx1, int ldw1,
    int K2, int ldx2, int ldw2,
    int N)
{
    __shared__ ushort As[TM][TK];
    __shared__ ushort Bs[TN][TK];
    const int tid = threadIdx.x;
    const int lane = tid & 63;
    const int wid = tid >> 6;            // 0..3
    const int wm = wid >> 1, wn = wid & 1;
    const int m0 = blockIdx.y * TM;
    const int n0 = blockIdx.x * TN;

    const int srow = wid * 32 + (lane >> 2);   // staging source row within tile
    const int skc  = (lane & 3) * 8;           // staging k elem offset

    f32x4 acc[4][4] = {};

    for (int phase = 0; phase < 2; ++phase) {
        const ushort* X = phase ? X2 : X1;
        const ushort* W = phase ? W2 : W1;
        const int K   = phase ? K2 : K1;
        const int ldx = phase ? ldx2 : ldx1;
        const int ldw = phase ? ldw2 : ldw1;
        if (X == nullptr || K == 0) continue;

        for (int k0 = 0; k0 < K; k0 += TK) {
            gload16(X + (size_t)(m0 + srow) * ldx + k0 + skc,      &As[wid * 32][0]);
            gload16(X + (size_t)(m0 + srow + 16) * ldx + k0 + skc, &As[wid * 32 + 16][0]);
            gload16(W + (size_t)(n0 + srow) * ldw + k0 + skc,      &Bs[wid * 32][0]);
            gload16(W + (size_t)(n0 + srow + 16) * ldw + k0 + skc, &Bs[wid * 32 + 16][0]);
            __syncthreads();

            s16x8 a[4], b[4];
            #pragma unroll
            for (int m = 0; m < 4; ++m)
                a[m] = *(const s16x8*)&As[wm * 64 + m * 16 + (lane & 15)][(lane >> 4) * 8];
            #pragma unroll
            for (int n = 0; n < 4; ++n)
                b[n] = *(const s16x8*)&Bs[wn * 64 + n * 16 + (lane & 15)][(lane >> 4) * 8];
            #pragma unroll
            for (int m = 0; m < 4; ++m)
                #pragma unroll
                for (int n = 0; n < 4; ++n)
                    acc[m][n] = __builtin_amdgcn_mfma_f32_16x16x32_bf16(a[m], b[n], acc[m][n], 0, 0, 0);
            __syncthreads();
        }
    }

    #pragma unroll
    for (int m = 0; m < 4; ++m) {
        #pragma unroll
        for (int n = 0; n < 4; ++n) {
            int col = n0 + wn * 64 + n * 16 + (lane & 15);
            float bsum = (bias1 ? bias1[col] : 0.f) + (bias2 ? bias2[col] : 0.f);
            #pragma unroll
            for (int j = 0; j < 4; ++j) {
                int row = m0 + wm * 64 + m * 16 + (lane >> 4) * 4 + j;
                float v = acc[m][n][j] + bsum;
                if (Cf) Cf[(size_t)row * N + col] = v;
                if (Cb) Cb[(size_t)row * N + col] = f2bf(v);
            }
        }
    }
}

// ---------------- softmax over T=512 per row (f32 in, f32 out) ----------------
__global__ __launch_bounds__(256) void softmax_kernel(
    const float* __restrict__ logits, float* __restrict__ aw)
{
    int b = blockIdx.x;
    const float* row = logits + (size_t)b * T;
    int tid = threadIdx.x;
    float v0 = row[tid];
    float v1 = row[tid + 256];
    float m = fmaxf(v0, v1);
    #pragma unroll
    for (int off = 32; off > 0; off >>= 1) m = fmaxf(m, __shfl_down(m, off, 64));
    __shared__ float sm[4];
    __shared__ float ss[4];
    if ((tid & 63) == 0) sm[tid >> 6] = m;
    __syncthreads();
    m = fmaxf(fmaxf(sm[0], sm[1]), fmaxf(sm[2], sm[3]));
    float e0 = expf(v0 - m), e1 = expf(v1 - m);
    float s = e0 + e1;
    #pragma unroll
    for (int off = 32; off > 0; off >>= 1) s += __shfl_down(s, off, 64);
    if ((tid & 63) == 0) ss[tid >> 6] = s;
    __syncthreads();
    s = ss[0] + ss[1] + ss[2] + ss[3];
    float inv = 1.0f / s;
    aw[(size_t)b * T + tid]       = e0 * inv;
    aw[(size_t)b * T + tid + 256] = e1 * inv;
}

// ---------------- ctx[b][h] = sum_t aw[b][t] * enc[t][b][h]  (bf16 out) ----------------
__global__ __launch_bounds__(256) void ctx_kernel(
    const float* __restrict__ enc, const float* __restrict__ aw,
    ushort* __restrict__ ctx_bf)
{
    int b = blockIdx.x;
    __shared__ float w[T];
    for (int t = threadIdx.x; t < T; t += 256) w[t] = aw[(size_t)b * T + t];
    __syncthreads();
    int h0i = threadIdx.x * 4;
    const float* p = enc + (size_t)b * H + h0i;
    float4 acc = {0.f, 0.f, 0.f, 0.f};
    #pragma unroll 8
    for (int t = 0; t < T; ++t) {
        float4 v = *(const float4*)(p + (size_t)t * B * H);
        float s = w[t];
        acc.x += s * v.x; acc.y += s * v.y; acc.z += s * v.z; acc.w += s * v.w;
    }
    ushort4 o;
    o.x = f2bf(acc.x); o.y = f2bf(acc.y); o.z = f2bf(acc.z); o.w = f2bf(acc.w);
    ((ushort4*)(ctx_bf + (size_t)b * H))[threadIdx.x] = o;
}

// ---------------- LSTM pointwise: gates (i,f,g,o) -> h,c ----------------
__device__ __forceinline__ float sigmf(float v) { return 1.0f / (1.0f + expf(-v)); }

__global__ __launch_bounds__(256) void lstm_pointwise_kernel(
    const float* __restrict__ g, const float* __restrict__ c_in,
    float* __restrict__ h_out, float* __restrict__ c_out,
    ushort* __restrict__ h_bf)
{
    int idx = blockIdx.x * 256 + threadIdx.x;   // 0 .. B*H-1
    int b = idx >> 10;
    int j = idx & 1023;
    const float* gr = g + (size_t)b * G4;
    float gi = gr[j];
    float gf = gr[j + H];
    float gc = gr[j + 2 * H];
    float go = gr[j + 3 * H];
    float c = sigmf(gf) * c_in[idx] + sigmf(gi) * tanhf(gc);
    float h = sigmf(go) * tanhf(c);
    h_out[idx] = h;
    c_out[idx] = c;
    if (h_bf) h_bf[idx] = f2bf(h);
}

// ---------------- pred: out[b] = dot(h2[b], pred_w) + pred_b ----------------
__global__ __launch_bounds__(256) void pred_kernel(
    const float* __restrict__ h2, const float* __restrict__ pw,
    const float* __restrict__ pb, float* __restrict__ out)
{
    int b = blockIdx.x;
    const float* row = h2 + (size_t)b * H;
    float s = 0.f;
    for (int j = threadIdx.x; j < H; j += 256) s += row[j] * pw[j];
    #pragma unroll
    for (int off = 32; off > 0; off >>= 1) s += __shfl_down(s, off, 64);
    __shared__ float sm[4];
    if ((threadIdx.x & 63) == 0) sm[threadIdx.x >> 6] = s;
    __syncthreads();
    if (threadIdx.x == 0) out[b] = sm[0] + sm[1] + sm[2] + sm[3] + pb[0];
}

extern "C" void kernel_launch(void* const* d_in, const int* in_sizes, int n_in,
                              void* d_out, int out_size, void* d_ws, size_t ws_size,
                              hipStream_t stream) {
    (void)in_sizes; (void)n_in; (void)out_size; (void)ws_size;
    const float* x      = (const float*)d_in[0];
    const int*   x_emb  = (const int*)d_in[1];
    const float* h0     = (const float*)d_in[2];   // (2,B,H)
    const float* c0     = (const float*)d_in[3];
    const float* enc    = (const float*)d_in[4];   // (T,B,H)
    const float* emb0   = (const float*)d_in[5];
    const float* emb1   = (const float*)d_in[6];
    const float* emb2   = (const float*)d_in[7];
    const float* emb3   = (const float*)d_in[8];
    const float* attn_w = (const float*)d_in[9];   // (T, 2176)
    const float* attn_b = (const float*)d_in[10];
    const float* comb_w = (const float*)d_in[11];  // (128, 1152)
    const float* comb_b = (const float*)d_in[12];
    const float* w_ih0  = (const float*)d_in[13];  // (4096,128)
    const float* w_hh0  = (const float*)d_in[14];  // (4096,1024)
    const float* b_ih0  = (const float*)d_in[15];
    const float* b_hh0  = (const float*)d_in[16];
    const float* w_ih1  = (const float*)d_in[17];  // (4096,1024)
    const float* w_hh1  = (const float*)d_in[18];
    const float* b_ih1  = (const float*)d_in[19];
    const float* b_hh1  = (const float*)d_in[20];
    const float* pred_w = (const float*)d_in[21];  // (1,1024)
    const float* pred_b = (const float*)d_in[22];

    float* out = (float*)d_out;
    const size_t BH = (size_t)B * H;           // 1048576
    float* h1_out = out + 1024;                // h_stack[0]
    float* h2_out = out + 1024 + BH;           // h_stack[1]
    float* c1_out = out + 1024 + 2 * BH;       // c_stack[0]
    float* c2_out = out + 1024 + 3 * BH;       // c_stack[1]
    float* aw_out = out + 1024 + 4 * BH;       // (B,T)

    char* w = (char*)d_ws;
    ushort* attn_in_bf = (ushort*)w;  w += (size_t)B * AK * 2;        // 4,456,448
    ushort* h0_bf      = (ushort*)w;  w += (size_t)2 * BH * 2;        // 4,194,304
    ushort* attn_w_bf  = (ushort*)w;  w += (size_t)T * AK * 2;        // 2,228,224
    ushort* comb_w_bf  = (ushort*)w;  w += (size_t)IN * (IN + H) * 2; // 294,912
    ushort* wih0_bf    = (ushort*)w;  w += (size_t)G4 * IN * 2;       // 1,048,576
    ushort* whh0_bf    = (ushort*)w;  w += (size_t)G4 * H * 2;        // 8,388,608
    ushort* wih1_bf    = (ushort*)w;  w += (size_t)G4 * H * 2;
    ushort* whh1_bf    = (ushort*)w;  w += (size_t)G4 * H * 2;
    ushort* ctx_bf     = (ushort*)w;  w += (size_t)BH * 2;            // 2,097,152
    ushort* comb_bf    = (ushort*)w;  w += (size_t)B * IN * 2;        // 262,144
    ushort* h1_bf      = (ushort*)w;  w += (size_t)BH * 2;
    float*  logits     = (float*)w;   w += (size_t)B * T * 4;         // 2,097,152
    float*  g          = (float*)w;   w += (size_t)B * G4 * 4;        // 16,777,216

    #define CVT(src, dst, n) f32_to_bf16_kernel<<<((n)/4 + 255)/256, 256, 0, stream>>>(src, dst, (n)/4)
    CVT(h0,     h0_bf,     2 * B * H);
    CVT(attn_w, attn_w_bf, T * AK);
    CVT(comb_w, comb_w_bf, IN * (IN + H));
    CVT(w_ih0,  wih0_bf,   G4 * IN);
    CVT(w_hh0,  whh0_bf,   G4 * H);
    CVT(w_ih1,  wih1_bf,   G4 * H);
    CVT(w_hh1,  whh1_bf,   G4 * H);
    #undef CVT

    build_attn_in_kernel<<<B, 256, 0, stream>>>(x, x_emb, h0, c0, emb0, emb1, emb2, emb3, attn_in_bf);

    // logits = attn_in @ attn_w^T + attn_b   (1024 x 512, K=2176)
    mfma_gemm_kernel<<<dim3(T / TN, B / TM), 256, 0, stream>>>(
        attn_in_bf, attn_w_bf, nullptr, nullptr, attn_b, nullptr, logits, nullptr,
        AK, AK, AK, 0, 0, 0, T);

    softmax_kernel<<<B, 256, 0, stream>>>(logits, aw_out);

    ctx_kernel<<<B, 256, 0, stream>>>(enc, aw_out, ctx_bf);

    // comb = [x_rnn | ctx] @ comb_w^T + comb_b   (1024 x 128) -> bf16
    mfma_gemm_kernel<<<dim3(IN / TN, B / TM), 256, 0, stream>>>(
        attn_in_bf, comb_w_bf, ctx_bf, comb_w_bf + IN, comb_b, nullptr, nullptr, comb_bf,
        IN, AK, IN + H, H, H, IN + H, IN);

    // g1 = comb @ w_ih0^T + h0[0] @ w_hh0^T + b_ih0 + b_hh0   (1024 x 4096)
    mfma_gemm_kernel<<<dim3(G4 / TN, B / TM), 256, 0, stream>>>(
        comb_bf, wih0_bf, h0_bf, whh0_bf, b_ih0, b_hh0, g, nullptr,
        IN, IN, IN, H, H, H, G4);

    lstm_pointwise_kernel<<<(B * H) / 256, 256, 0, stream>>>(g, c0, h1_out, c1_out, h1_bf);

    // g2 = h1 @ w_ih1^T + h0[1] @ w_hh1^T + b_ih1 + b_hh1
    mfma_gemm_kernel<<<dim3(G4 / TN, B / TM), 256, 0, stream>>>(
        h1_bf, wih1_bf, h0_bf + BH, whh1_bf, b_ih1, b_hh1, g, nullptr,
        H, H, H, H, H, H, G4);

    lstm_pointwise_kernel<<<(B * H) / 256, 256, 0, stream>>>(g, c0 + BH, h2_out, c2_out, nullptr);

    pred_kernel<<<B, 256, 0, stream>>>(h2_out, pred_w, pred_b, out);
}

// Round 3
// 644.358 us; speedup vs baseline: 1.6309x; 1.0418x over previous
//
#include <hip/hip_runtime.h>
#include <hip/hip_bf16.h>

#define B 1024
#define H 1024
#define T 512
#define NUM 44
#define IN 128
#define AK (IN + 2 * H)   // 2176
#define XC (IN + H)       // 1152
#define G4 (4 * H)        // 4096

typedef __attribute__((ext_vector_type(8))) short s16x8;
typedef __attribute__((ext_vector_type(4))) float f32x4;

__device__ __forceinline__ unsigned short f2bf(float f) {
    unsigned u = __float_as_uint(f);
    unsigned r = (u + 0x7fffu + ((u >> 16) & 1u)) >> 16;
    return (unsigned short)r;
}

__device__ __forceinline__ void gload16(const ushort* g, ushort* l) {
    __builtin_amdgcn_global_load_lds(
        (const __attribute__((address_space(1))) void*)g,
        (__attribute__((address_space(3))) void*)l,
        16, 0, 0);
}

#define TM 128
#define TN 128
#define TK 32

// ---------------- shared GEMM tile core (single phase, C = X@W^T [+Cin][+b1][+b2]) ----------------
__device__ __forceinline__ void gemm_core(
    const ushort* __restrict__ X, const ushort* __restrict__ W,
    const float* __restrict__ bias1, const float* __restrict__ bias2,
    const float* __restrict__ Cin, float* __restrict__ Cf, ushort* __restrict__ Cb,
    int kbeg, int kend, int ldx, int ldw, int ldc,
    int m0, int n0, ushort (*As)[TK], ushort (*Bs)[TK])
{
    const int tid = threadIdx.x;
    const int lane = tid & 63;
    const int wid = tid >> 6;
    const int wm = wid >> 1, wn = wid & 1;
    const int srow = wid * 32 + (lane >> 2);
    const int skc  = (lane & 3) * 8;

    f32x4 acc[4][4] = {};

    for (int k0 = kbeg; k0 < kend; k0 += TK) {
        gload16(X + (size_t)(m0 + srow) * ldx + k0 + skc,      &As[wid * 32][0]);
        gload16(X + (size_t)(m0 + srow + 16) * ldx + k0 + skc, &As[wid * 32 + 16][0]);
        gload16(W + (size_t)(n0 + srow) * ldw + k0 + skc,      &Bs[wid * 32][0]);
        gload16(W + (size_t)(n0 + srow + 16) * ldw + k0 + skc, &Bs[wid * 32 + 16][0]);
        __syncthreads();

        s16x8 a[4], b[4];
        #pragma unroll
        for (int m = 0; m < 4; ++m)
            a[m] = *(const s16x8*)&As[wm * 64 + m * 16 + (lane & 15)][(lane >> 4) * 8];
        #pragma unroll
        for (int n = 0; n < 4; ++n)
            b[n] = *(const s16x8*)&Bs[wn * 64 + n * 16 + (lane & 15)][(lane >> 4) * 8];
        #pragma unroll
        for (int m = 0; m < 4; ++m)
            #pragma unroll
            for (int n = 0; n < 4; ++n)
                acc[m][n] = __builtin_amdgcn_mfma_f32_16x16x32_bf16(a[m], b[n], acc[m][n], 0, 0, 0);
        __syncthreads();
    }

    #pragma unroll
    for (int m = 0; m < 4; ++m) {
        #pragma unroll
        for (int n = 0; n < 4; ++n) {
            int col = n0 + wn * 64 + n * 16 + (lane & 15);
            float badd = (bias1 ? bias1[col] : 0.f) + (bias2 ? bias2[col] : 0.f);
            #pragma unroll
            for (int j = 0; j < 4; ++j) {
                int row = m0 + wm * 64 + m * 16 + (lane >> 4) * 4 + j;
                float v = acc[m][n][j] + badd;
                if (Cin) v += Cin[(size_t)row * ldc + col];
                if (Cf) Cf[(size_t)row * ldc + col] = v;
                if (Cb) Cb[(size_t)row * ldc + col] = f2bf(v);
            }
        }
    }
}

// ---------------- standalone GEMM (with optional split-K via blockIdx.z) ----------------
__global__ __launch_bounds__(256) void gemm_kernel(
    const ushort* __restrict__ X, const ushort* __restrict__ W,
    const float* __restrict__ bias1, const float* __restrict__ bias2,
    const float* __restrict__ Cin, float* __restrict__ Cf, ushort* __restrict__ Cb,
    int Kchunk, int ldx, int ldw, int ldc, size_t Czstride)
{
    __shared__ ushort As[TM][TK];
    __shared__ ushort Bs[TN][TK];
    int kbeg = blockIdx.z * Kchunk;
    gemm_core(X, W, bias1, bias2, Cin,
              Cf ? Cf + (size_t)blockIdx.z * Czstride : nullptr, Cb,
              kbeg, kbeg + Kchunk, ldx, ldw, ldc,
              blockIdx.y * TM, blockIdx.x * TN, As, Bs);
}

// ---------------- merged f32 -> bf16 converts (6 segments, float4 units) ----------------
#define CN0 524288   // h0: 2*B*H/4
#define CN1 278528   // attn_w: T*AK/4
#define CN2 131072   // w_ih0: G4*IN/4
#define CN3 1048576  // w_hh0: G4*H/4
#define CN4 1048576  // w_ih1
#define CN5 1048576  // w_hh1
#define CNT (CN0+CN1+CN2+CN3+CN4+CN5)

__global__ __launch_bounds__(256) void convert_all_kernel(
    const float* __restrict__ s0, const float* __restrict__ s1, const float* __restrict__ s2,
    const float* __restrict__ s3, const float* __restrict__ s4, const float* __restrict__ s5,
    ushort* __restrict__ d0, ushort* __restrict__ d1, ushort* __restrict__ d2,
    ushort* __restrict__ d3, ushort* __restrict__ d4, ushort* __restrict__ d5)
{
    int i = blockIdx.x * 256 + threadIdx.x;
    const float* s; ushort* d;
    if (i < CN0) { s = s0; d = d0; }
    else if ((i -= CN0) < CN1) { s = s1; d = d1; }
    else if ((i -= CN1) < CN2) { s = s2; d = d2; }
    else if ((i -= CN2) < CN3) { s = s3; d = d3; }
    else if ((i -= CN3) < CN4) { s = s4; d = d4; }
    else if ((i -= CN4) < CN5) { s = s5; d = d5; }
    else return;
    float4 v = ((const float4*)s)[i];
    ushort4 o;
    o.x = f2bf(v.x); o.y = f2bf(v.y); o.z = f2bf(v.z); o.w = f2bf(v.w);
    ((ushort4*)d)[i] = o;
}

// ---------------- comb_w (128 x 1152) -> transposed bf16 (1152 x 128) ----------------
__global__ __launch_bounds__(256) void transpose_combw_kernel(
    const float* __restrict__ comb_w, ushort* __restrict__ outT)
{
    int idx = blockIdx.x * 256 + threadIdx.x;   // 0 .. 147455
    int j = idx >> 7;      // 0..1151
    int k = idx & 127;     // 0..127
    outT[idx] = f2bf(comb_w[(size_t)k * XC + j]);
}

// ---------------- bias_f[i] = w_ih0[i]·comb_b + b_ih0[i] + b_hh0[i] ----------------
__global__ __launch_bounds__(256) void bias_f_kernel(
    const float* __restrict__ w_ih0, const float* __restrict__ comb_b,
    const float* __restrict__ b_ih0, const float* __restrict__ b_hh0,
    float* __restrict__ biasf)
{
    __shared__ float cb[IN];
    int i = blockIdx.x * 256 + threadIdx.x;     // 0..4095
    for (int j = threadIdx.x; j < IN; j += 256) cb[j] = comb_b[j];
    __syncthreads();
    float s = b_ih0[i] + b_hh0[i];
    const float* row = w_ih0 + (size_t)i * IN;
    #pragma unroll 8
    for (int j = 0; j < IN; ++j) s += row[j] * cb[j];
    biasf[i] = s;
}

// ---------------- build attn_in (bf16) + xctx[:, :128] ----------------
__global__ __launch_bounds__(256) void build_attn_in_kernel(
    const float* __restrict__ x, const int* __restrict__ x_emb,
    const float* __restrict__ h0, const float* __restrict__ c0,
    const float* __restrict__ e0, const float* __restrict__ e1,
    const float* __restrict__ e2, const float* __restrict__ e3,
    ushort* __restrict__ attn_in, ushort* __restrict__ xctx)
{
    int b = blockIdx.x;
    int id0 = x_emb[b * 4 + 0];
    int id1 = x_emb[b * 4 + 1];
    int id2 = x_emb[b * 4 + 2];
    int id3 = x_emb[b * 4 + 3];
    ushort* dst = attn_in + (size_t)b * AK;
    for (int j = threadIdx.x; j < AK; j += 256) {
        float v;
        if (j < 44)        v = x[b * NUM + j];
        else if (j < 108)  v = e0[id0 * 64 + (j - 44)];
        else if (j < 116)  v = e1[id1 * 8 + (j - 108)];
        else if (j < 124)  v = e2[id2 * 8 + (j - 116)];
        else if (j < 128)  v = e3[id3 * 4 + (j - 124)];
        else if (j < 1152) v = h0[b * H + (j - 128)];
        else               v = c0[b * H + (j - 1152)];
        unsigned short bf = f2bf(v);
        dst[j] = bf;
        if (j < IN) xctx[(size_t)b * XC + j] = bf;
    }
}

// ---------------- MEGA: hh0 GEMM | hh1 GEMM | W_f GEMM | ctx(+softmax) ----------------
// blocks [0,256): hh0   [256,512): hh1   [512,800): W_f   [800,1824): ctx
__global__ __launch_bounds__(256) void mega_kernel(
    const ushort* __restrict__ h0_bf, const ushort* __restrict__ whh0_bf,
    const ushort* __restrict__ whh1_bf, float* __restrict__ g1buf, float* __restrict__ g2buf,
    const ushort* __restrict__ wih0_bf, const ushort* __restrict__ comb_wT_bf,
    ushort* __restrict__ W_f_bf,
    const float* __restrict__ logits_part, const float* __restrict__ attn_b,
    float* __restrict__ aw_out, const float* __restrict__ enc, ushort* __restrict__ xctx)
{
    __shared__ union {
        struct { ushort As[TM][TK]; ushort Bs[TN][TK]; } g;
        struct { float w[T]; float red[8]; } c;
    } sh;

    const int bid = blockIdx.x;
    if (bid < 512) {
        // hh GEMM: g_hh = h0[layer] @ w_hh^T   (1024 x 4096, K=1024)
        int layer = bid >> 8;
        int t = bid & 255;
        int m0 = (t >> 5) * TM;
        int n0 = (t & 31) * TN;
        gemm_core(h0_bf + (size_t)layer * B * H, layer ? whh1_bf : whh0_bf,
                  nullptr, nullptr, nullptr, layer ? g2buf : g1buf, nullptr,
                  0, H, H, H, G4, m0, n0, sh.g.As, sh.g.Bs);
    } else if (bid < 800) {
        // W_f = w_ih0 @ comb_w  (4096 x 1152, K=128) -> bf16
        int t = bid - 512;
        int m0 = (t / 9) * TM;
        int n0 = (t % 9) * TN;
        gemm_core(wih0_bf, comb_wT_bf, nullptr, nullptr, nullptr, nullptr, W_f_bf,
                  0, IN, IN, IN, XC, m0, n0, sh.g.As, sh.g.Bs);
    } else {
        // ctx + softmax for row b
        int b = bid - 800;
        int tid = threadIdx.x;
        float v0 = attn_b[tid], v1 = attn_b[tid + 256];
        #pragma unroll
        for (int z = 0; z < 4; ++z) {
            const float* lp = logits_part + (size_t)z * B * T + (size_t)b * T;
            v0 += lp[tid];
            v1 += lp[tid + 256];
        }
        float m = fmaxf(v0, v1);
        #pragma unroll
        for (int off = 32; off > 0; off >>= 1) m = fmaxf(m, __shfl_down(m, off, 64));
        if ((tid & 63) == 0) sh.c.red[tid >> 6] = m;
        __syncthreads();
        m = fmaxf(fmaxf(sh.c.red[0], sh.c.red[1]), fmaxf(sh.c.red[2], sh.c.red[3]));
        float e0 = expf(v0 - m), e1 = expf(v1 - m);
        float s = e0 + e1;
        #pragma unroll
        for (int off = 32; off > 0; off >>= 1) s += __shfl_down(s, off, 64);
        if ((tid & 63) == 0) sh.c.red[4 + (tid >> 6)] = s;
        __syncthreads();
        s = sh.c.red[4] + sh.c.red[5] + sh.c.red[6] + sh.c.red[7];
        float inv = 1.0f / s;
        float w0 = e0 * inv, w1 = e1 * inv;
        sh.c.w[tid] = w0;
        sh.c.w[tid + 256] = w1;
        aw_out[(size_t)b * T + tid]       = w0;
        aw_out[(size_t)b * T + tid + 256] = w1;
        __syncthreads();

        int h0i = tid * 4;
        const float* p = enc + (size_t)b * H + h0i;
        float4 acc = {0.f, 0.f, 0.f, 0.f};
        #pragma unroll 8
        for (int t = 0; t < T; ++t) {
            float4 v = *(const float4*)(p + (size_t)t * B * H);
            float sw = sh.c.w[t];
            acc.x += sw * v.x; acc.y += sw * v.y; acc.z += sw * v.z; acc.w += sw * v.w;
        }
        ushort4 o;
        o.x = f2bf(acc.x); o.y = f2bf(acc.y); o.z = f2bf(acc.z); o.w = f2bf(acc.w);
        *(ushort4*)(xctx + (size_t)b * XC + IN + h0i) = o;
    }
}

// ---------------- LSTM pointwise ----------------
__device__ __forceinline__ float sigmf(float v) { return 1.0f / (1.0f + expf(-v)); }

__global__ __launch_bounds__(256) void lstm_pointwise_kernel(
    const float* __restrict__ g, const float* __restrict__ c_in,
    float* __restrict__ h_out, float* __restrict__ c_out,
    ushort* __restrict__ h_bf)
{
    int idx = blockIdx.x * 256 + threadIdx.x;
    int b = idx >> 10;
    int j = idx & 1023;
    const float* gr = g + (size_t)b * G4;
    float gi = gr[j];
    float gf = gr[j + H];
    float gc = gr[j + 2 * H];
    float go = gr[j + 3 * H];
    float c = sigmf(gf) * c_in[idx] + sigmf(gi) * tanhf(gc);
    float h = sigmf(go) * tanhf(c);
    h_out[idx] = h;
    c_out[idx] = c;
    if (h_bf) h_bf[idx] = f2bf(h);
}

// ---------------- pred ----------------
__global__ __launch_bounds__(256) void pred_kernel(
    const float* __restrict__ h2, const float* __restrict__ pw,
    const float* __restrict__ pb, float* __restrict__ out)
{
    int b = blockIdx.x;
    const float* row = h2 + (size_t)b * H;
    float s = 0.f;
    for (int j = threadIdx.x; j < H; j += 256) s += row[j] * pw[j];
    #pragma unroll
    for (int off = 32; off > 0; off >>= 1) s += __shfl_down(s, off, 64);
    __shared__ float sm[4];
    if ((threadIdx.x & 63) == 0) sm[threadIdx.x >> 6] = s;
    __syncthreads();
    if (threadIdx.x == 0) out[b] = sm[0] + sm[1] + sm[2] + sm[3] + pb[0];
}

extern "C" void kernel_launch(void* const* d_in, const int* in_sizes, int n_in,
                              void* d_out, int out_size, void* d_ws, size_t ws_size,
                              hipStream_t stream) {
    (void)in_sizes; (void)n_in; (void)out_size; (void)ws_size;
    const float* x      = (const float*)d_in[0];
    const int*   x_emb  = (const int*)d_in[1];
    const float* h0     = (const float*)d_in[2];
    const float* c0     = (const float*)d_in[3];
    const float* enc    = (const float*)d_in[4];
    const float* emb0   = (const float*)d_in[5];
    const float* emb1   = (const float*)d_in[6];
    const float* emb2   = (const float*)d_in[7];
    const float* emb3   = (const float*)d_in[8];
    const float* attn_w = (const float*)d_in[9];
    const float* attn_b = (const float*)d_in[10];
    const float* comb_w = (const float*)d_in[11];
    const float* comb_b = (const float*)d_in[12];
    const float* w_ih0  = (const float*)d_in[13];
    const float* w_hh0  = (const float*)d_in[14];
    const float* b_ih0  = (const float*)d_in[15];
    const float* b_hh0  = (const float*)d_in[16];
    const float* w_ih1  = (const float*)d_in[17];
    const float* w_hh1  = (const float*)d_in[18];
    const float* b_ih1  = (const float*)d_in[19];
    const float* b_hh1  = (const float*)d_in[20];
    const float* pred_w = (const float*)d_in[21];
    const float* pred_b = (const float*)d_in[22];

    float* out = (float*)d_out;
    const size_t BH = (size_t)B * H;
    float* h1_out = out + 1024;
    float* h2_out = out + 1024 + BH;
    float* c1_out = out + 1024 + 2 * BH;
    float* c2_out = out + 1024 + 3 * BH;
    float* aw_out = out + 1024 + 4 * BH;

    char* w = (char*)d_ws;
    ushort* attn_in_bf = (ushort*)w;  w += (size_t)B * AK * 2;
    ushort* h0_bf      = (ushort*)w;  w += (size_t)2 * BH * 2;
    ushort* attn_w_bf  = (ushort*)w;  w += (size_t)T * AK * 2;
    ushort* wih0_bf    = (ushort*)w;  w += (size_t)G4 * IN * 2;
    ushort* whh0_bf    = (ushort*)w;  w += (size_t)G4 * H * 2;
    ushort* wih1_bf    = (ushort*)w;  w += (size_t)G4 * H * 2;
    ushort* whh1_bf    = (ushort*)w;  w += (size_t)G4 * H * 2;
    ushort* comb_wT_bf = (ushort*)w;  w += (size_t)XC * IN * 2;
    ushort* W_f_bf     = (ushort*)w;  w += (size_t)G4 * XC * 2;
    float*  bias_f     = (float*)w;   w += (size_t)G4 * 4;
    ushort* xctx_bf    = (ushort*)w;  w += (size_t)B * XC * 2;
    ushort* h1_bf      = (ushort*)w;  w += (size_t)BH * 2;
    float*  logits_p   = (float*)w;   w += (size_t)4 * B * T * 4;
    float*  g1buf      = (float*)w;   w += (size_t)B * G4 * 4;
    float*  g2buf      = (float*)w;   w += (size_t)B * G4 * 4;
    // total ~93 MB

    convert_all_kernel<<<(CNT + 255) / 256, 256, 0, stream>>>(
        h0, attn_w, w_ih0, w_hh0, w_ih1, w_hh1,
        h0_bf, attn_w_bf, wih0_bf, whh0_bf, wih1_bf, whh1_bf);

    transpose_combw_kernel<<<(XC * IN) / 256, 256, 0, stream>>>(comb_w, comb_wT_bf);

    bias_f_kernel<<<G4 / 256, 256, 0, stream>>>(w_ih0, comb_b, b_ih0, b_hh0, bias_f);

    build_attn_in_kernel<<<B, 256, 0, stream>>>(x, x_emb, h0, c0, emb0, emb1, emb2, emb3,
                                                attn_in_bf, xctx_bf);

    // logits partials: split-K=4 over K=2176 (chunk 544)
    gemm_kernel<<<dim3(T / TN, B / TM, 4), 256, 0, stream>>>(
        attn_in_bf, attn_w_bf, nullptr, nullptr, nullptr, logits_p, nullptr,
        544, AK, AK, T, (size_t)B * T);

    // MEGA: hh0 + hh1 + W_f GEMMs overlapped with ctx (+softmax)
    mega_kernel<<<1824, 256, 0, stream>>>(
        h0_bf, whh0_bf, whh1_bf, g1buf, g2buf,
        wih0_bf, comb_wT_bf, W_f_bf,
        logits_p, attn_b, aw_out, enc, xctx_bf);

    // g1 = xctx @ W_f^T + g_hh0 + bias_f   (1024 x 4096, K=1152)
    gemm_kernel<<<dim3(G4 / TN, B / TM, 1), 256, 0, stream>>>(
        xctx_bf, W_f_bf, bias_f, nullptr, g1buf, g1buf, nullptr,
        XC, XC, XC, G4, 0);

    lstm_pointwise_kernel<<<(B * H) / 256, 256, 0, stream>>>(g1buf, c0, h1_out, c1_out, h1_bf);

    // g2 = h1 @ w_ih1^T + g_hh1 + b_ih1 + b_hh1   (1024 x 4096, K=1024)
    gemm_kernel<<<dim3(G4 / TN, B / TM, 1), 256, 0, stream>>>(
        h1_bf, wih1_bf, b_ih1, b_hh1, g2buf, g2buf, nullptr,
        H, H, H, G4, 0);

    lstm_pointwise_kernel<<<(B * H) / 256, 256, 0, stream>>>(g2buf, c0 + BH, h2_out, c2_out, nullptr);

    pred_kernel<<<B, 256, 0, stream>>>(h2_out, pred_w, pred_b, out);
}